// Round 8
// baseline (236.230 us; speedup 1.0000x reference)
//
#include <hip/hip_runtime.h>
#include <hip/hip_bf16.h>

// Problem constants (fixed by setup_inputs)
#define BS   4
#define NQ   6400
#define DIMS 256
#define NH   8
#define NP   4
#define GW   80
#define GH   80

typedef __hip_bfloat16 bf16;
typedef unsigned short ushort;
typedef __attribute__((ext_vector_type(8))) short short8;   // 8 bf16 (MFMA A/B frag)
typedef __attribute__((ext_vector_type(4))) float floatx4;  // MFMA C/D frag

union bfu { bf16 h; ushort s; };
__device__ __forceinline__ ushort f2bs(float x) { bfu u; u.h = __float2bfloat16(x); return u.s; }
__device__ __forceinline__ float bs2f(ushort s) { return __uint_as_float(((unsigned)s) << 16); }
__device__ __forceinline__ float ldin(const void* p, size_t i, int isf) {
    return isf ? ((const float*)p)[i] : bs2f(((const ushort*)p)[i]);
}

// ---------------------------------------------------------------------------
// dtype detector: f32-packed data read as bf16 shows impossible exponents.
// ---------------------------------------------------------------------------
__global__ void detect_k(const ushort* __restrict__ q, int* flag) {
    __shared__ int s;
    if (threadIdx.x == 0) s = 0;
    __syncthreads();
    int bad = 0;
    for (int j = 0; j < 16; ++j) {
        ushort v = q[threadIdx.x * 16 + j];
        int e = (v >> 7) & 0xFF;
        if (e > 160) bad = 1;
    }
    if (bad) atomicOr(&s, 1);
    __syncthreads();
    if (threadIdx.x == 0) *flag = s;
}

// ---------------------------------------------------------------------------
// prep: fused input-convert (cvt) + weight transpose/convert (wprep).
// blocks [0,6400): query/voxbev -> bf16 (skip if already bf16)
// blocks [6400,7299): weights -> bf16 B^T[n][k]; biases -> f32
// ---------------------------------------------------------------------------
__global__ __launch_bounds__(256) void prep_k(
    const void* __restrict__ query, const void* __restrict__ voxbev,
    const void* __restrict__ Wv, const void* __restrict__ bv,
    const void* __restrict__ Woff, const void* __restrict__ boff,
    const void* __restrict__ Wattn, const void* __restrict__ battn,
    const void* __restrict__ Wo, const void* __restrict__ bo,
    const int* __restrict__ flagp,
    uint4* __restrict__ qb, uint4* __restrict__ vbv,
    ushort* __restrict__ WvT, ushort* __restrict__ WoaT, ushort* __restrict__ WoT,
    float* __restrict__ biasv, float* __restrict__ biasoa, float* __restrict__ biaso)
{
    const int isf = *flagp;
    if (blockIdx.x < 6400) {
        if (!isf) return;
        const int t = blockIdx.x * 256 + threadIdx.x;
        const int half = 819200;
        const void* src = (t < half) ? query : voxbev;
        uint4* dst = (t < half) ? qb : vbv;
        const int j = (t < half) ? t : t - half;
        const float4* s = (const float4*)src + (size_t)j * 2;
        float4 a = s[0], b = s[1];
        uint4 o;
        o.x = ((unsigned)f2bs(a.y) << 16) | f2bs(a.x);
        o.y = ((unsigned)f2bs(a.w) << 16) | f2bs(a.z);
        o.z = ((unsigned)f2bs(b.y) << 16) | f2bs(b.x);
        o.w = ((unsigned)f2bs(b.w) << 16) | f2bs(b.z);
        dst[j] = o;
        return;
    }
    const int i = (blockIdx.x - 6400) * 256 + threadIdx.x;
    const int n1 = 256 * 256, n2 = n1 + 192 * 512, n3 = n2 + 256 * 256;
    const int n4 = n3 + 256, n5 = n4 + 192, n6 = n5 + 256;
    if (i < n1) {
        int n = i >> 8, k = i & 255;
        WvT[i] = f2bs(ldin(Wv, (size_t)k * 256 + n, isf));
    } else if (i < n2) {
        int j = i - n1, n = j >> 9, k = j & 511;
        float v = (n < 128) ? ldin(Woff, (size_t)k * 128 + n, isf)
                            : ldin(Wattn, (size_t)k * 64 + (n - 128), isf);
        WoaT[j] = f2bs(v);
    } else if (i < n3) {
        int j = i - n2, n = j >> 8, k = j & 255;
        WoT[j] = f2bs(ldin(Wo, (size_t)k * 256 + n, isf));
    } else if (i < n4) {
        biasv[i - n3] = ldin(bv, i - n3, isf);
    } else if (i < n5) {
        int j = i - n4;
        biasoa[j] = (j < 128) ? ldin(boff, j, isf) : ldin(battn, j - 128, isf);
    } else if (i < n6) {
        biaso[i - n5] = ldin(bo, i - n5, isf);
    }
}

// ---------------------------------------------------------------------------
// GEMM body: block = 128 rows x full N, acc for ALL N in registers.
//  - 4 waves, wave wv owns rows wv*32..wv*32+31 (2 m-frags of 16).
//  - B staged as 64-col panels (64 x 256 shorts, padded stride 264 -> <=2-way
//    LDS conflicts = free); per panel: 8 k-iters x (2 A-glb + 4 B-ds + 8 MFMA)
//    = 32 wave-MFMA per barrier pair.
//  - A fragments read DIRECTLY from global in MFMA layout: lanes {r,r+16,
//    r+32,r+48} consume full 64B lines; A bytes touched exactly once.
//  - Epilogue per n-tile via f32 LDS bounce (stride 67) -> full-line stores.
// ---------------------------------------------------------------------------
enum { A_VAL = 0, A_QCAT = 1, A_PLAIN = 2 };
enum { O_BF16 = 0, O_FINAL = 1 };

template <int AMODE, int OMODE, int KTOT, int NTILES>
__device__ __forceinline__ void gemm_body(
    int bm, const ushort* __restrict__ Apl, const ushort* __restrict__ BT,
    const float* __restrict__ biasf, void* __restrict__ C,
    const ushort* __restrict__ qsrc, const ushort* __restrict__ vsrc,
    int isf, char* smem)
{
    constexpr int N = NTILES * 64;
    constexpr int NPH = KTOT / 256;
    short* pan = (short*)smem;
    float* cbf = (float*)smem;

    const int tid = threadIdx.x;
    const int lane = tid & 63, wv = tid >> 6;
    const int wm = wv * 32;
    const int fr = lane & 15, fq = (lane >> 4) * 8;

    // A row pointers (lo: k<256, hi: k>=256 for QCAT)
    const ushort* alo[2]; const ushort* ahi[2] = {nullptr, nullptr};
    #pragma unroll
    for (int mt = 0; mt < 2; ++mt) {
        const int row = bm + wm + mt * 16 + fr;
        if (AMODE == A_PLAIN) {
            alo[mt] = Apl + (size_t)row * DIMS;
        } else if (AMODE == A_VAL) {
            const int bq = row / NQ, q = row - bq * NQ;
            alo[mt] = ((bq & 1) ? vsrc : qsrc) + (size_t)((bq >> 1) * NQ + q) * DIMS;
        } else {
            const int b = row / NQ, q = row - (row / NQ) * NQ;
            alo[mt] = ((b & 1) ? vsrc : qsrc) + (size_t)((b >> 1) * NQ + q) * DIMS;
            ahi[mt] = qsrc + (size_t)(b * NQ + q) * DIMS;
        }
    }

    floatx4 acc[2][NTILES * 4] = {};

    #pragma unroll
    for (int nt = 0; nt < NTILES; ++nt) {
        #pragma unroll
        for (int ph = 0; ph < NPH; ++ph) {
            __syncthreads();
            // stage panel: thread reads 128B contiguous of one B row
            #pragma unroll
            for (int i = 0; i < 8; ++i) {
                const int c = tid * 8 + i;
                const int row = c >> 5, j = (c & 31) * 8;
                *(uint4*)&pan[row * 264 + j] =
                    *(const uint4*)&BT[(size_t)(nt * 64 + row) * KTOT + ph * 256 + j];
            }
            __syncthreads();

            const ushort* ar0 = (AMODE == A_QCAT && ph == 1) ? ahi[0] : alo[0];
            const ushort* ar1 = (AMODE == A_QCAT && ph == 1) ? ahi[1] : alo[1];
            #pragma unroll
            for (int k0 = 0; k0 < 256; k0 += 32) {
                short8 af0 = *(const short8*)&ar0[k0 + fq];
                short8 af1 = *(const short8*)&ar1[k0 + fq];
                short8 bf[4];
                #pragma unroll
                for (int nf = 0; nf < 4; ++nf)
                    bf[nf] = *(const short8*)&pan[(nf * 16 + fr) * 264 + k0 + fq];
                #pragma unroll
                for (int nf = 0; nf < 4; ++nf) {
                    acc[0][nt * 4 + nf] = __builtin_amdgcn_mfma_f32_16x16x32_bf16(
                        af0, bf[nf], acc[0][nt * 4 + nf], 0, 0, 0);
                    acc[1][nt * 4 + nf] = __builtin_amdgcn_mfma_f32_16x16x32_bf16(
                        af1, bf[nf], acc[1][nt * 4 + nf], 0, 0, 0);
                }
            }
        }
    }

    // epilogue per n-tile. C/D layout: col=lane&15, row=(lane>>4)*4+reg.
    const int col = lane & 15, rq4 = (lane >> 4) * 4;
    #pragma unroll
    for (int nt = 0; nt < NTILES; ++nt) {
        __syncthreads();
        #pragma unroll
        for (int mt = 0; mt < 2; ++mt)
            #pragma unroll
            for (int nf = 0; nf < 4; ++nf)
                #pragma unroll
                for (int r = 0; r < 4; ++r)
                    cbf[(wm + mt * 16 + rq4 + r) * 67 + nf * 16 + col] =
                        acc[mt][nt * 4 + nf][r];
        __syncthreads();

        if (OMODE == O_FINAL && isf) {
            // f32 out: 16 lanes x 16B = full 256B row-chunk
            const int r16 = tid >> 4, cc = tid & 15;
            #pragma unroll
            for (int it = 0; it < 8; ++it) {
                const int lr = it * 16 + r16;
                const size_t g = (size_t)(bm + lr);
                const int gc = nt * 64 + cc * 4;
                float4 x = *(const float4*)&cbf[lr * 67 + cc * 4];
                const ushort* rs = qsrc + g * DIMS + gc;
                x.x += biasf[gc + 0] + bs2f(rs[0]);
                x.y += biasf[gc + 1] + bs2f(rs[1]);
                x.z += biasf[gc + 2] + bs2f(rs[2]);
                x.w += biasf[gc + 3] + bs2f(rs[3]);
                *(float4*)((float*)C + g * N + gc) = x;
            }
        } else {
            // bf16 out: 8 lanes x 16B = full 128B row-chunk
            const int r8 = tid >> 3, c8 = tid & 7;
            #pragma unroll
            for (int it = 0; it < 4; ++it) {
                const int lr = it * 32 + r8;
                const size_t g = (size_t)(bm + lr);
                const int gc = nt * 64 + c8 * 8;
                float4 x0 = *(const float4*)&cbf[lr * 67 + c8 * 8];
                float4 x1 = *(const float4*)&cbf[lr * 67 + c8 * 8 + 4];
                float xs[8] = { x0.x, x0.y, x0.z, x0.w, x1.x, x1.y, x1.z, x1.w };
                #pragma unroll
                for (int e = 0; e < 8; ++e) xs[e] += biasf[gc + e];
                if (OMODE == O_FINAL) {
                    const ushort* rs = qsrc + g * DIMS + gc;
                    #pragma unroll
                    for (int e = 0; e < 8; ++e) xs[e] += bs2f(rs[e]);
                }
                uint4 o;
                o.x = ((unsigned)f2bs(xs[1]) << 16) | f2bs(xs[0]);
                o.y = ((unsigned)f2bs(xs[3]) << 16) | f2bs(xs[2]);
                o.z = ((unsigned)f2bs(xs[5]) << 16) | f2bs(xs[4]);
                o.w = ((unsigned)f2bs(xs[7]) << 16) | f2bs(xs[6]);
                *(uint4*)((ushort*)C + g * N + gc) = o;
            }
        }
    }
}

// merged GEMM1 (value proj, 400 blocks) + GEMM2 (off/attn, 200 blocks)
__global__ __launch_bounds__(256) void proj_k(
    const ushort* __restrict__ WvT, const float* __restrict__ biasv,
    ushort* __restrict__ v_ws,
    const ushort* __restrict__ WoaT, const float* __restrict__ biasoa,
    ushort* __restrict__ offraw,
    const void* __restrict__ query_raw, const void* __restrict__ voxbev_raw,
    const ushort* __restrict__ qb, const ushort* __restrict__ vbv,
    const int* __restrict__ flagp)
{
    __shared__ __align__(16) char smem[34368];
    const int isf = *flagp;
    const ushort* qsrc = isf ? qb  : (const ushort*)query_raw;
    const ushort* vsrc = isf ? vbv : (const ushort*)voxbev_raw;
    if (blockIdx.x < 400)
        gemm_body<A_VAL, O_BF16, 256, 4>(blockIdx.x * 128, nullptr, WvT, biasv,
                                         (void*)v_ws, qsrc, vsrc, isf, smem);
    else
        gemm_body<A_QCAT, O_BF16, 512, 3>((blockIdx.x - 400) * 128, nullptr, WoaT,
                                          biasoa, (void*)offraw, qsrc, vsrc, isf, smem);
}

// GEMM4: out = sampled @ Wo + bo + residual(bf16 query)
__global__ __launch_bounds__(256) void gemm4_k(
    const ushort* __restrict__ sampled, const ushort* __restrict__ WoT,
    const float* __restrict__ biaso, void* __restrict__ C,
    const void* __restrict__ query_raw,
    const ushort* __restrict__ qb, const int* __restrict__ flagp)
{
    __shared__ __align__(16) char smem[34368];
    const int isf = *flagp;
    const ushort* qsrc = isf ? qb : (const ushort*)query_raw;
    gemm_body<A_PLAIN, O_FINAL, 256, 4>(blockIdx.x * 128, sampled, WoT, biaso,
                                        C, qsrc, nullptr, isf, smem);
}

// ---------------------------------------------------------------------------
// Fused softmax + coords + bilinear sampling + queue mean.
// Phase 2 batches all 16 corner loads per queue into registers before
// consuming -> ~16 outstanding loads/thread (concurrency-bound fix).
// Block = 8 queries of ONE batch (XCD-swizzled).
// ---------------------------------------------------------------------------
__global__ __launch_bounds__(256) void sample_k(
    const ushort* __restrict__ v,        // [BS*2, NQ, 256] bf16
    const ushort* __restrict__ offraw,   // [BS*NQ, 192] bf16
    const void* __restrict__ refpts,     // [BS*2, NQ, 1, 2] input dtype
    const int* __restrict__ flagp,
    ushort* __restrict__ sampled)        // [BS*NQ, 256] bf16
{
    const int isf = *flagp;
    __shared__ float sx[8][2][8][4], sy[8][2][8][4], sw[8][2][8][4];
    const int tid = threadIdx.x;
    const int j = blockIdx.x;
    const int slot = j & 7;
    const int b = slot >> 1;
    const int idx = ((j >> 3) << 1) + (slot & 1);    // 0..799
    const int q0 = idx * 8;

    if (tid < 128) {
        const int lq = tid >> 4, queue = (tid >> 3) & 1, h = tid & 7;
        const int q = q0 + lq;
        const int gq = b * NQ + q;
        const ushort* row = offraw + (size_t)gq * 192;
        const ushort* al = row + 128 + h * 8 + queue * 4;
        float l0 = bs2f(al[0]), l1 = bs2f(al[1]), l2 = bs2f(al[2]), l3 = bs2f(al[3]);
        float mx = fmaxf(fmaxf(l0, l1), fmaxf(l2, l3));
        float e0 = __expf(l0 - mx), e1 = __expf(l1 - mx);
        float e2 = __expf(l2 - mx), e3 = __expf(l3 - mx);
        float inv = 0.5f / (e0 + e1 + e2 + e3);      // fold queue-mean 0.5
        const int bq = b * 2 + queue;
        const float rx = ldin(refpts, ((size_t)bq * NQ + q) * 2 + 0, isf);
        const float ry = ldin(refpts, ((size_t)bq * NQ + q) * 2 + 1, isf);
        const ushort* od = row + h * 16 + queue * 8;
        float ww[4] = { e0 * inv, e1 * inv, e2 * inv, e3 * inv };
        #pragma unroll
        for (int p = 0; p < NP; ++p) {
            sx[lq][queue][h][p] = rx * (float)GW + bs2f(od[p * 2 + 0]) - 0.5f;
            sy[lq][queue][h][p] = ry * (float)GH + bs2f(od[p * 2 + 1]) - 0.5f;
            sw[lq][queue][h][p] = ww[p];
        }
    }
    __syncthreads();

    const int lq = tid >> 5, h = (tid >> 2) & 7, d8 = tid & 3;
    const int gq = b * NQ + q0 + lq;
    const int doff = h * 32 + d8 * 8;
    float a[8] = {};
    #pragma unroll
    for (int queue = 0; queue < 2; ++queue) {
        const ushort* vb = v + (size_t)(b * 2 + queue) * NQ * DIMS;
        float cw[16];
        int pix[16];
        #pragma unroll
        for (int p = 0; p < NP; ++p) {
            const float x = sx[lq][queue][h][p];
            const float y = sy[lq][queue][h][p];
            const float w = sw[lq][queue][h][p];
            const float x0f = floorf(x), y0f = floorf(y);
            const float dx = x - x0f, dy = y - y0f;
            const int x0 = (int)x0f, y0 = (int)y0f;
            const float c4[4] = { w * (1.0f - dx) * (1.0f - dy),
                                  w * dx * (1.0f - dy),
                                  w * (1.0f - dx) * dy,
                                  w * dx * dy };
            #pragma unroll
            for (int c = 0; c < 4; ++c) {
                const int xs = x0 + (c & 1), ys = y0 + (c >> 1);
                const bool ok = (unsigned)xs < (unsigned)GW && (unsigned)ys < (unsigned)GH;
                const int xi = min(max(xs, 0), GW - 1);
                const int yi = min(max(ys, 0), GH - 1);
                cw[p * 4 + c] = ok ? c4[c] : 0.0f;
                pix[p * 4 + c] = yi * GW + xi;
            }
        }
        // batched gathers: 16 independent loads in flight
        uint4 d[16];
        #pragma unroll
        for (int i = 0; i < 16; ++i)
            d[i] = *(const uint4*)&vb[(size_t)pix[i] * DIMS + doff];
        #pragma unroll
        for (int i = 0; i < 16; ++i) {
            const float c = cw[i];
            a[0] += c * bs2f((ushort)d[i].x); a[1] += c * bs2f((ushort)(d[i].x >> 16));
            a[2] += c * bs2f((ushort)d[i].y); a[3] += c * bs2f((ushort)(d[i].y >> 16));
            a[4] += c * bs2f((ushort)d[i].z); a[5] += c * bs2f((ushort)(d[i].z >> 16));
            a[6] += c * bs2f((ushort)d[i].w); a[7] += c * bs2f((ushort)(d[i].w >> 16));
        }
    }
    uint4 o;
    o.x = ((unsigned)f2bs(a[1]) << 16) | f2bs(a[0]);
    o.y = ((unsigned)f2bs(a[3]) << 16) | f2bs(a[2]);
    o.z = ((unsigned)f2bs(a[5]) << 16) | f2bs(a[4]);
    o.w = ((unsigned)f2bs(a[7]) << 16) | f2bs(a[6]);
    *(uint4*)&sampled[(size_t)gq * DIMS + doff] = o;
}

// ---------------------------------------------------------------------------
extern "C" void kernel_launch(void* const* d_in, const int* in_sizes, int n_in,
                              void* d_out, int out_size, void* d_ws, size_t ws_size,
                              hipStream_t stream)
{
    const void* query  = d_in[0];
    const void* voxbev = d_in[1];
    const void* refpts = d_in[2];
    // d_in[3] spatial_shapes=[[80,80]], d_in[4] level_start_index=[0]: hardcoded
    const void* Wv   = d_in[5];  const void* bv    = d_in[6];
    const void* Woff = d_in[7];  const void* boff  = d_in[8];
    const void* Wattn= d_in[9];  const void* battn = d_in[10];
    const void* Wo   = d_in[11]; const void* bo    = d_in[12];

    // workspace (~59.8 MB, within proven budget)
    char* p = (char*)d_ws;
    int* flag = (int*)p;             p += 256;
    ushort* WvT  = (ushort*)p;       p += 256 * 256 * 2;
    ushort* WoaT = (ushort*)p;       p += 192 * 512 * 2;
    ushort* WoT  = (ushort*)p;       p += 256 * 256 * 2;
    float* biasv  = (float*)p;       p += 1024;
    float* biasoa = (float*)p;       p += 1024;
    float* biaso  = (float*)p;       p += 1024;
    ushort* qb   = (ushort*)p;       p += (size_t)BS * NQ * DIMS * 2;       // 13.1 MB
    ushort* vbv  = (ushort*)p;       p += (size_t)BS * NQ * DIMS * 2;       // 13.1 MB
    ushort* v_ws = (ushort*)p;       p += (size_t)2 * BS * NQ * DIMS * 2;   // 26.2 MB
    ushort* offraw = (ushort*)p;     p += (size_t)BS * NQ * 192 * 2;        //  9.8 MB
    ushort* sampled = (ushort*)p;    // 13.1 MB

    // 0. dtype detect, then fused convert+weight-prep
    detect_k<<<1, 256, 0, stream>>>((const ushort*)query, flag);
    prep_k<<<7299, 256, 0, stream>>>(query, voxbev, Wv, bv, Woff, boff,
                                     Wattn, battn, Wo, bo, flag,
                                     (uint4*)qb, (uint4*)vbv,
                                     WvT, WoaT, WoT, biasv, biasoa, biaso);

    // 1+2. merged: v = value @ Wv + bv  AND  offraw = qcat @ [Woff|Wattn]+bias
    proj_k<<<600, 256, 0, stream>>>(WvT, biasv, v_ws, WoaT, biasoa, offraw,
                                    query, voxbev, qb, vbv, flag);

    // 3. fused softmax + coords + bilinear sampling + queue mean
    sample_k<<<3200, 256, 0, stream>>>(v_ws, offraw, refpts, flag, sampled);

    // 4. out = sampled @ Wo + bo + residual
    gemm4_k<<<200, 256, 0, stream>>>(sampled, WoT, biaso, d_out, query, qb, flag);
}